// Round 3
// baseline (625.919 us; speedup 1.0000x reference)
//
#include <hip/hip_runtime.h>
#include <math.h>

#define BB 4
#define SS 2048
#define DD 512
#define NN 16
#define LL 4
#define VV 256
#define CC 128           // scan chunks: 512-block grids for scan kernels
#define TT (SS / CC)     // 16 steps per chunk
#define EPSL 1e-5f
#define MM (BB * SS)     // 8192 rows
#define KI 16            // K-iterations = 512/32
#define LPAD 528         // padded LDS row stride (floats)

typedef __bf16 bf16;
typedef __attribute__((ext_vector_type(8))) __bf16 bf16x8;
typedef __attribute__((ext_vector_type(4))) __bf16 bf16x4;
typedef __attribute__((ext_vector_type(4))) float f32x4;

// Packed fragment layout for a [rows][512] bf16 matrix:
//   tile = row>>4, fm = row&15, ki = k>>5, fq = (k>>3)&3, e = k&7
//   flat = tile*8192 + ki*512 + fq*128 + fm*8 + e
// => one MFMA fragment = 1KB contiguous; global_load_lds stages it with
//    per-lane global addr (base + lane*16B) and ds_read_b128 at lane*16B
//    is stride-1 (2 lanes/bank = conflict-free).

#define GLD_LDS(g, l) \
    __builtin_amdgcn_global_load_lds((__attribute__((address_space(1))) void*)(void*)(g), \
                                     (__attribute__((address_space(3))) void*)(l), 16, 0, 0)

// ---------------- shared LN row epilogue (wave holds one row of 512) -------
__device__ __forceinline__ void ln_row_write(float4 v0, float4 v1, int lane, size_t row,
                                             const float* __restrict__ gamma,
                                             const float* __restrict__ beta,
                                             float* HN, bf16* HNb) {
    float s = v0.x + v0.y + v0.z + v0.w + v1.x + v1.y + v1.z + v1.w;
    float q = v0.x * v0.x + v0.y * v0.y + v0.z * v0.z + v0.w * v0.w +
              v1.x * v1.x + v1.y * v1.y + v1.z * v1.z + v1.w * v1.w;
#pragma unroll
    for (int o = 1; o < 64; o <<= 1) {
        s += __shfl_xor(s, o);
        q += __shfl_xor(q, o);
    }
    float m = s * (1.0f / DD);
    float var = q * (1.0f / DD) - m * m;
    float rs = rsqrtf(var + EPSL);
    float4 g0 = *(const float4*)(gamma + lane * 4);
    float4 g1 = *(const float4*)(gamma + 256 + lane * 4);
    float4 b0 = *(const float4*)(beta + lane * 4);
    float4 b1 = *(const float4*)(beta + 256 + lane * 4);
    float4 o0, o1;
    o0.x = (v0.x - m) * rs * g0.x + b0.x;
    o0.y = (v0.y - m) * rs * g0.y + b0.y;
    o0.z = (v0.z - m) * rs * g0.z + b0.z;
    o0.w = (v0.w - m) * rs * g0.w + b0.w;
    o1.x = (v1.x - m) * rs * g1.x + b1.x;
    o1.y = (v1.y - m) * rs * g1.y + b1.y;
    o1.z = (v1.z - m) * rs * g1.z + b1.z;
    o1.w = (v1.w - m) * rs * g1.w + b1.w;
    float* hr = HN + row * DD;
    *(float4*)(hr + lane * 4) = o0;
    *(float4*)(hr + 256 + lane * 4) = o1;
    size_t pb = (size_t)(row >> 4) * 8192 + (size_t)(lane >> 3) * 512 +
                (size_t)((lane & 7) >> 1) * 128 + (row & 15) * 8 + (lane & 1) * 4;
    bf16x4 p0 = {(bf16)o0.x, (bf16)o0.y, (bf16)o0.z, (bf16)o0.w};
    bf16x4 p1 = {(bf16)o1.x, (bf16)o1.y, (bf16)o1.z, (bf16)o1.w};
    *(bf16x4*)(HNb + pb) = p0;
    *(bf16x4*)(HNb + pb + 8 * 512) = p1;
}

// ---------------- embed + layer-0 LN: X, HN, packed HNb in one pass --------
__global__ void embed_ln(const int* __restrict__ ids,
                         const float* __restrict__ eb,
                         const float* __restrict__ ep,
                         const float* __restrict__ gamma,
                         const float* __restrict__ beta,
                         float* __restrict__ X, float* HN, bf16* HNb) {
    int wave = threadIdx.x >> 6;
    int lane = threadIdx.x & 63;
    size_t row = blockIdx.x * 4 + wave;
    int s = (int)(row & (SS - 1));
    int id = ids[row];
    const float* ebr = eb + (size_t)id * DD;
    const float* epr = ep + (size_t)s * DD;
    float4 e0 = *(const float4*)(ebr + lane * 4);
    float4 e1 = *(const float4*)(ebr + 256 + lane * 4);
    float4 p0 = *(const float4*)(epr + lane * 4);
    float4 p1 = *(const float4*)(epr + 256 + lane * 4);
    float4 v0 = {e0.x + p0.x, e0.y + p0.y, e0.z + p0.z, e0.w + p0.w};
    float4 v1 = {e1.x + p1.x, e1.y + p1.y, e1.z + p1.z, e1.w + p1.w};
    *(float4*)(X + row * DD + lane * 4) = v0;
    *(float4*)(X + row * DD + 256 + lane * 4) = v1;
    ln_row_write(v0, v1, lane, row, gamma, beta, HN, HNb);
}

// ---------------- weight convert: coalesced LDS-slab transpose -> packed ---
// blk 0..255: layer n-tiles (l = blk>>6, tile = blk&63; tile<32 -> Wd, else WDp)
// blk 256..271: head n-tiles from Wh
__global__ __launch_bounds__(256) void convert_weights(const float* __restrict__ Wd,
                                                       const float* __restrict__ WDp,
                                                       const float* __restrict__ Wh,
                                                       bf16* __restrict__ WtP) {
    __shared__ float slab[512 * 17];
    int blk = blockIdx.x;
    const float* src;
    int nsrc, col0;
    bf16* dst;
    if (blk < 256) {
        int l = blk >> 6, tile = blk & 63;
        src = (tile < 32) ? (Wd + (size_t)l * DD * DD) : (WDp + (size_t)l * DD * DD);
        col0 = (tile & 31) * 16;
        nsrc = DD;
        dst = WtP + ((size_t)l * 64 + tile) * 8192;
    } else {
        int tile = blk - 256;
        src = Wh;
        col0 = tile * 16;
        nsrc = VV;
        dst = WtP + (size_t)(256 + tile) * 8192;
    }
    int tid = threadIdx.x;
    int kr = tid >> 2, cq = tid & 3;
#pragma unroll
    for (int i = 0; i < 8; i++) {
        int k = i * 64 + kr;
        float4 v = *(const float4*)(src + (size_t)k * nsrc + col0 + cq * 4);
        slab[k * 17 + cq * 4 + 0] = v.x;
        slab[k * 17 + cq * 4 + 1] = v.y;
        slab[k * 17 + cq * 4 + 2] = v.z;
        slab[k * 17 + cq * 4 + 3] = v.w;
    }
    __syncthreads();
#pragma unroll
    for (int it = 0; it < 4; it++) {
        int c = it * 256 + tid;
        int ki = c >> 6, fq = (c >> 4) & 3, fm = c & 15;
        int k0 = ki * 32 + fq * 8;
        bf16x8 v;
#pragma unroll
        for (int e = 0; e < 8; e++) v[e] = (bf16)slab[(k0 + e) * 17 + fm];
        *(bf16x8*)(dst + (size_t)c * 8) = v;
    }
}

// ---------------- MFMA GEMM: 128x128 tile, packed frags, LDS-staged --------
// 4 waves in 2x2; each wave owns a 64x64 quadrant (4x4 16x16 frags).
// Per K-step (BK=32): each wave stages 2 A + 2 B tile-fragments (1 KB each,
// one global_load_lds(16B) per fragment) -> 16 MFMA : 8 ds_read_b128.
// MODE 0 (head, NB=2): O1 = acc + bias (Nout cols)
// MODE 1 (layer, NB=8): col<512 -> DEL=softplus; col>=512 -> D2=+bias2+Xres
template <int MODE, int NB>
__global__ __launch_bounds__(256) void gemm128(const bf16* __restrict__ Ap,
                                               const bf16* __restrict__ Bp,
                                               const float* __restrict__ bias,
                                               const float* __restrict__ bias2,
                                               const float* __restrict__ Xres,
                                               float* __restrict__ O1,
                                               float* __restrict__ O2, int Nout) {
    __shared__ bf16 As[8 * 512];   // 8 KB: 8 row-tile fragments
    __shared__ bf16 Bs[8 * 512];   // 8 KB: 8 col-tile fragments
    const int tid = threadIdx.x, wave = tid >> 6, lane = tid & 63;
    const int nb = blockIdx.x >> 6;        // n-tile (128 cols)
    const int ms = blockIdx.x & 63;        // m-strip (128 rows)
    const int wr = wave >> 1, wc = wave & 1;

    const bf16* gA0 = Ap + ((size_t)ms * 8 + wave) * 8192 + lane * 8;
    const bf16* gA1 = gA0 + (size_t)4 * 8192;
    const bf16* gB0 = Bp + ((size_t)nb * 8 + wave) * 8192 + lane * 8;
    const bf16* gB1 = gB0 + (size_t)4 * 8192;
    bf16* lA0 = As + wave * 512;
    bf16* lA1 = As + (wave + 4) * 512;
    bf16* lB0 = Bs + wave * 512;
    bf16* lB1 = Bs + (wave + 4) * 512;

    f32x4 acc[4][4];
#pragma unroll
    for (int i = 0; i < 4; i++)
#pragma unroll
        for (int j = 0; j < 4; j++) acc[i][j] = (f32x4){0.f, 0.f, 0.f, 0.f};

    for (int ki = 0; ki < KI; ki++) {
        GLD_LDS(gA0 + ki * 512, lA0);
        GLD_LDS(gA1 + ki * 512, lA1);
        GLD_LDS(gB0 + ki * 512, lB0);
        GLD_LDS(gB1 + ki * 512, lB1);
        __syncthreads();
        bf16x8 af[4], bfr[4];
#pragma unroll
        for (int i = 0; i < 4; i++)
            af[i] = *(const bf16x8*)(As + (wr * 4 + i) * 512 + lane * 8);
#pragma unroll
        for (int j = 0; j < 4; j++)
            bfr[j] = *(const bf16x8*)(Bs + (wc * 4 + j) * 512 + lane * 8);
#pragma unroll
        for (int i = 0; i < 4; i++)
#pragma unroll
            for (int j = 0; j < 4; j++)
                acc[i][j] = __builtin_amdgcn_mfma_f32_16x16x32_bf16(af[i], bfr[j], acc[i][j], 0, 0, 0);
        __syncthreads();
    }

    const int fm = lane & 15, fq = lane >> 4;
#pragma unroll
    for (int i = 0; i < 4; i++) {
#pragma unroll
        for (int j = 0; j < 4; j++) {
            int col = (nb * 8 + wc * 4 + j) * 16 + fm;
#pragma unroll
            for (int r = 0; r < 4; r++) {
                int row = (ms * 8 + wr * 4 + i) * 16 + fq * 4 + r;
                float v = acc[i][j][r];
                if (MODE == 0) {
                    O1[(size_t)row * Nout + col] = v + bias[col];
                } else {
                    if (col < DD) {
                        v += bias[col];
                        v = fmaxf(v, 0.0f) + log1pf(__expf(-fabsf(v)));
                        O1[(size_t)row * DD + col] = v;
                    } else {
                        int c = col - DD;
                        O2[(size_t)row * DD + c] = v + bias2[c] + Xres[(size_t)row * DD + c];
                    }
                }
            }
        }
    }
}

// ---------------- fp32 B/C projection: [8192x512] x [512x32] ---------------
// Block: 32 rows x 32 cols, 256 threads, 4 rows/thread -> each W LDS read
// feeds 4 FMAs (4x fewer ds_read_b32 than 1 row/thread). Grid 256 = 1
// block/CU. W staged [k][32] (broadcast across row-groups, conflict-free).
__global__ __launch_bounds__(256) void bcproj(const float* __restrict__ HN,
                                              const float* __restrict__ WB,
                                              const float* __restrict__ bB,
                                              const float* __restrict__ WC,
                                              const float* __restrict__ bC,
                                              float* __restrict__ BIo,
                                              float* __restrict__ CIo) {
    __shared__ float W[512 * 32];   // 64 KB
    int tid = threadIdx.x;
#pragma unroll
    for (int i = 0; i < 8; i++) {
        int f = i * 256 + tid;          // float4 index into WB/WC (2048 each)
        int k = f >> 2, c4 = (f & 3) * 4;
        float4 v = *(const float4*)(WB + (size_t)f * 4);
        W[k * 32 + c4 + 0] = v.x;
        W[k * 32 + c4 + 1] = v.y;
        W[k * 32 + c4 + 2] = v.z;
        W[k * 32 + c4 + 3] = v.w;
        float4 u = *(const float4*)(WC + (size_t)f * 4);
        W[k * 32 + 16 + c4 + 0] = u.x;
        W[k * 32 + 16 + c4 + 1] = u.y;
        W[k * 32 + 16 + c4 + 2] = u.z;
        W[k * 32 + 16 + c4 + 3] = u.w;
    }
    __syncthreads();
    int rg = tid >> 5, c = tid & 31;
    size_t row0 = (size_t)blockIdx.x * 32 + rg * 4;
    const float* h0 = HN + row0 * DD;
    const float* h1 = h0 + DD;
    const float* h2 = h1 + DD;
    const float* h3 = h2 + DD;
    float a0 = 0.f, a1 = 0.f, a2 = 0.f, a3 = 0.f;
#pragma unroll 4
    for (int k = 0; k < DD; k += 4) {
        float4 v0 = *(const float4*)(h0 + k);
        float4 v1 = *(const float4*)(h1 + k);
        float4 v2 = *(const float4*)(h2 + k);
        float4 v3 = *(const float4*)(h3 + k);
        float w0 = W[(k + 0) * 32 + c];
        float w1 = W[(k + 1) * 32 + c];
        float w2 = W[(k + 2) * 32 + c];
        float w3 = W[(k + 3) * 32 + c];
        a0 = fmaf(v0.x, w0, a0); a0 = fmaf(v0.y, w1, a0);
        a0 = fmaf(v0.z, w2, a0); a0 = fmaf(v0.w, w3, a0);
        a1 = fmaf(v1.x, w0, a1); a1 = fmaf(v1.y, w1, a1);
        a1 = fmaf(v1.z, w2, a1); a1 = fmaf(v1.w, w3, a1);
        a2 = fmaf(v2.x, w0, a2); a2 = fmaf(v2.y, w1, a2);
        a2 = fmaf(v2.z, w2, a2); a2 = fmaf(v2.w, w3, a2);
        a3 = fmaf(v3.x, w0, a3); a3 = fmaf(v3.y, w1, a3);
        a3 = fmaf(v3.z, w2, a3); a3 = fmaf(v3.w, w3, a3);
    }
    if (c < NN) {
        float bb = bB[c];
        BIo[(row0 + 0) * NN + c] = a0 + bb;
        BIo[(row0 + 1) * NN + c] = a1 + bb;
        BIo[(row0 + 2) * NN + c] = a2 + bb;
        BIo[(row0 + 3) * NN + c] = a3 + bb;
    } else {
        int cc = c - NN;
        float bb = bC[cc];
        CIo[(row0 + 0) * NN + cc] = a0 + bb;
        CIo[(row0 + 1) * NN + cc] = a1 + bb;
        CIo[(row0 + 2) * NN + cc] = a2 + bb;
        CIo[(row0 + 3) * NN + cc] = a3 + bb;
    }
}

// ---------------- scan phase 1: pure register chunk scan --------------------
// Block (b,c): 512 threads (one per d). No big LDS; BI from bcproj (fp32).
// prod tracked as exp(Ar * sum(dl)) -- one exp per n at the end.
// P/LS stored at ((b*CC+c)*DD+d)*NN+n so stores AND scan2 loads coalesce.
__global__ __launch_bounds__(512) void scan1(const float* __restrict__ DEL,
                                             const float* __restrict__ HN,
                                             const float* __restrict__ BIc,
                                             const float* __restrict__ logA,
                                             float* __restrict__ P,
                                             float* __restrict__ LSt) {
    __shared__ float bis[TT * NN];   // 1 KB
    int b = blockIdx.x >> 7, c = blockIdx.x & (CC - 1);
    int d = threadIdx.x;
    size_t row0 = (size_t)b * SS + (size_t)c * TT;
    if (d < TT * NN) bis[d] = BIc[row0 * NN + d];
    float Ar[NN], st[NN];
    const float* la = logA + d * NN;
#pragma unroll
    for (int n = 0; n < NN; n += 4) {
        float4 a4 = *(const float4*)(la + n);
        Ar[n + 0] = -__expf(a4.x);
        Ar[n + 1] = -__expf(a4.y);
        Ar[n + 2] = -__expf(a4.z);
        Ar[n + 3] = -__expf(a4.w);
    }
#pragma unroll
    for (int n = 0; n < NN; n++) st[n] = 0.0f;
    float sdl = 0.0f;
    __syncthreads();
    const float* dp = DEL + row0 * DD + d;
    const float* hp = HN + row0 * DD + d;
#pragma unroll 4
    for (int tt = 0; tt < TT; tt++) {
        float dl = dp[(size_t)tt * DD];
        float du = dl * hp[(size_t)tt * DD];
        sdl += dl;
#pragma unroll
        for (int n = 0; n < NN; n++) {
            float a = __expf(dl * Ar[n]);
            st[n] = fmaf(a, st[n], du * bis[tt * NN + n]);
        }
    }
    size_t o = (((size_t)b * CC + c) * DD + d) * NN;
#pragma unroll
    for (int n = 0; n < NN; n += 4) {
        *(f32x4*)(P + o + n) = (f32x4){__expf(Ar[n] * sdl), __expf(Ar[n + 1] * sdl),
                                       __expf(Ar[n + 2] * sdl), __expf(Ar[n + 3] * sdl)};
        *(f32x4*)(LSt + o + n) = (f32x4){st[n], st[n + 1], st[n + 2], st[n + 3]};
    }
}

// ---------------- scan phase 2: parallel affine-compose combine ------------
// Block per (b,d): 256 threads = 16 n x 16 groups of 8 chunks. Each thread
// composes its 8 chunk-affines in registers; 16-wide LDS scan over groups;
// re-walk writes exclusive chunk-initial states into LS in place.
__global__ __launch_bounds__(256) void scan2(const float* __restrict__ P,
                                             float* __restrict__ LS) {
    __shared__ float sP[256], sL[256];
    int bd = blockIdx.x;                       // b*DD + d
    int b = bd >> 9, d = bd & (DD - 1);
    int n = threadIdx.x & (NN - 1), g = threadIdx.x >> 4;
    size_t base = ((size_t)b * CC * DD + d) * NN + n;
    const size_t cs = (size_t)DD * NN;         // stride between chunks
    float p[8], l[8];
#pragma unroll
    for (int i = 0; i < 8; i++) {
        size_t o = base + (size_t)(g * 8 + i) * cs;
        p[i] = P[o];
        l[i] = LS[o];
    }
    float FP = 1.0f, FL = 0.0f;
#pragma unroll
    for (int i = 0; i < 8; i++) {
        FL = fmaf(p[i], FL, l[i]);
        FP *= p[i];
    }
    sP[threadIdx.x] = FP;
    sL[threadIdx.x] = FL;
    __syncthreads();
    if (threadIdx.x < NN) {
        int nn = threadIdx.x;
        float s = 0.0f;
#pragma unroll
        for (int gg = 0; gg < 16; gg++) {
            float fp = sP[gg * 16 + nn];
            float fl = sL[gg * 16 + nn];
            sL[gg * 16 + nn] = s;              // exclusive group-initial state
            s = fmaf(fp, s, fl);
        }
    }
    __syncthreads();
    float s = sL[g * 16 + n];
#pragma unroll
    for (int i = 0; i < 8; i++) {
        size_t o = base + (size_t)(g * 8 + i) * cs;
        LS[o] = s;                             // chunk-initial state
        s = fmaf(p[i], s, l[i]);
    }
}

// ---------------- scan3 + fused next-layer LN -------------------------------
template <int LAST>
__global__ __launch_bounds__(512) void scan3ln(const float* __restrict__ DEL,
                                               float* HN,
                                               const float* __restrict__ BI,
                                               const float* __restrict__ CI,
                                               const float* __restrict__ logA,
                                               const float* __restrict__ SIN,
                                               const float* __restrict__ D2,
                                               const float* __restrict__ gamma,
                                               const float* __restrict__ beta,
                                               float* __restrict__ X,
                                               bf16* HNb) {
    __shared__ float xvs[TT * LPAD];    // 33.8 KB
    __shared__ float bis[TT * NN], cis[TT * NN];
    int b = blockIdx.x >> 7, c = blockIdx.x & (CC - 1);
    int d = threadIdx.x;
    size_t row0 = (size_t)b * SS + (size_t)c * TT;
    if (d < TT * NN) {
        bis[d] = BI[row0 * NN + d];
        cis[d] = CI[row0 * NN + d];
    }
    float Ar[NN], st[NN];
    size_t o = (((size_t)b * CC + c) * DD + d) * NN;
    const float* la = logA + d * NN;
#pragma unroll
    for (int n = 0; n < NN; n += 4) {
        float4 a4 = *(const float4*)(la + n);
        Ar[n + 0] = -__expf(a4.x);
        Ar[n + 1] = -__expf(a4.y);
        Ar[n + 2] = -__expf(a4.z);
        Ar[n + 3] = -__expf(a4.w);
        float4 s4 = *(const float4*)(SIN + o + n);
        st[n + 0] = s4.x;
        st[n + 1] = s4.y;
        st[n + 2] = s4.z;
        st[n + 3] = s4.w;
    }
    __syncthreads();
    const float* dp = DEL + row0 * DD + d;
    const float* hp = HN + row0 * DD + d;
    const float* d2p = D2 + row0 * DD + d;
    float* xp = X + row0 * DD + d;
#pragma unroll 4
    for (int tt = 0; tt < TT; tt++) {
        float dl = dp[(size_t)tt * DD];
        float du = dl * hp[(size_t)tt * DD];
        float y = 0.0f;
#pragma unroll
        for (int n = 0; n < NN; n++) {
            float a = __expf(dl * Ar[n]);
            st[n] = fmaf(a, st[n], du * bis[tt * NN + n]);
            y = fmaf(st[n], cis[tt * NN + n], y);
        }
        float xv = d2p[(size_t)tt * DD] + y;
        xvs[tt * LPAD + d] = xv;
        if (!LAST) xp[(size_t)tt * DD] = xv;
    }
    __syncthreads();
    int wv = d >> 6, lane = d & 63;
#pragma unroll
    for (int r = 0; r < 2; r++) {
        int tt = wv * 2 + r;
        size_t row = row0 + tt;
        const float* xr = xvs + tt * LPAD;
        float4 v0 = *(const float4*)(xr + lane * 4);
        float4 v1 = *(const float4*)(xr + 256 + lane * 4);
        if (LAST) {
            size_t pb = (size_t)(row >> 4) * 8192 + (size_t)(lane >> 3) * 512 +
                        (size_t)((lane & 7) >> 1) * 128 + (row & 15) * 8 + (lane & 1) * 4;
            bf16x4 p0 = {(bf16)v0.x, (bf16)v0.y, (bf16)v0.z, (bf16)v0.w};
            bf16x4 p1 = {(bf16)v1.x, (bf16)v1.y, (bf16)v1.z, (bf16)v1.w};
            *(bf16x4*)(HNb + pb) = p0;
            *(bf16x4*)(HNb + pb + 8 * 512) = p1;
        } else {
            ln_row_write(v0, v1, lane, row, gamma, beta, HN, HNb);
        }
    }
}

extern "C" void kernel_launch(void* const* d_in, const int* in_sizes, int n_in,
                              void* d_out, int out_size, void* d_ws, size_t ws_size,
                              hipStream_t stream) {
    const int* ids = (const int*)d_in[0];
    const float* eb = (const float*)d_in[1];
    const float* ep = (const float*)d_in[2];
    const float* logA = (const float*)d_in[3];
    const float* Wd = (const float*)d_in[4];
    const float* bd = (const float*)d_in[5];
    const float* WB = (const float*)d_in[6];
    const float* bB = (const float*)d_in[7];
    const float* WC = (const float*)d_in[8];
    const float* bC = (const float*)d_in[9];
    const float* WDp = (const float*)d_in[10];
    const float* bDp = (const float*)d_in[11];
    const float* gamma = (const float*)d_in[12];
    const float* beta = (const float*)d_in[13];
    const float* Wh = (const float*)d_in[14];
    const float* bh = (const float*)d_in[15];
    float* out = (float*)d_out;

    size_t E = (size_t)MM * DD;                // 4,194,304 floats
    size_t EN = (size_t)MM * NN;               // 131,072
    // EC = B*CC*DD*NN == E exactly at CC=128.
    // Aliasing: P = X (X dead between gemm128 (reads Xres) and scan3ln
    // (rewrites all of X)); BIc/CIc live in d_out (dead until head writes).
    float* X = (float*)d_ws;
    float* HN = X + E;
    float* DEL = HN + E;
    float* D2 = DEL + E;
    float* LS = D2 + E;
    bf16* HNb = (bf16*)(LS + E);               // packed activations, 8 MB
    bf16* WtP = HNb + E;                       // packed weights: 272 tiles
    float* P = X;
    float* BIc = out;
    float* CIc = out + EN;

    embed_ln<<<MM / 4, 256, 0, stream>>>(ids, eb, ep, gamma, beta, X, HN, HNb);
    convert_weights<<<272, 256, 0, stream>>>(Wd, WDp, Wh, WtP);
    for (int l = 0; l < LL; l++) {
        const float* lA = logA + (size_t)l * DD * NN;
        bcproj<<<MM / 32, 256, 0, stream>>>(HN, WB + (size_t)l * DD * NN, bB + l * NN,
                                            WC + (size_t)l * DD * NN, bC + l * NN,
                                            BIc, CIc);
        gemm128<1, 8><<<512, 256, 0, stream>>>(
            HNb, WtP + (size_t)l * 524288, bd + l * DD, bDp + l * DD, X, DEL, D2, 1024);
        scan1<<<BB * CC, 512, 0, stream>>>(DEL, HN, BIc, lA, P, LS);
        scan2<<<BB * DD, 256, 0, stream>>>(P, LS);
        if (l < LL - 1) {
            scan3ln<0><<<BB * CC, 512, 0, stream>>>(DEL, HN, BIc, CIc, lA, LS, D2,
                                                    gamma + (l + 1) * DD, beta + (l + 1) * DD,
                                                    X, HNb);
        } else {
            scan3ln<1><<<BB * CC, 512, 0, stream>>>(DEL, HN, BIc, CIc, lA, LS, D2,
                                                    nullptr, nullptr, X, HNb);
        }
    }
    // head: reads packed bf16(X_final) written by last scan3ln
    gemm128<0, 2><<<128, 256, 0, stream>>>(
        HNb, WtP + (size_t)2097152, bh, nullptr, nullptr, out, nullptr, VV);
}

// Round 4
// 518.922 us; speedup vs baseline: 1.2062x; 1.2062x over previous
//
#include <hip/hip_runtime.h>
#include <math.h>

#define BB 4
#define SS 2048
#define DD 512
#define NN 16
#define LL 4
#define VV 256
#define CC 128           // scan chunks: 512-block grids for scan kernels
#define TT (SS / CC)     // 16 steps per chunk
#define EPSL 1e-5f
#define MM (BB * SS)     // 8192 rows
#define KI 16            // K-iterations = 512/32
#define LPAD 528         // padded LDS row stride (floats)

typedef __bf16 bf16;
typedef __attribute__((ext_vector_type(8))) __bf16 bf16x8;
typedef __attribute__((ext_vector_type(4))) __bf16 bf16x4;
typedef __attribute__((ext_vector_type(4))) float f32x4;

// Packed fragment layout for a [rows][512] bf16 matrix:
//   tile = row>>4, fm = row&15, ki = k>>5, fq = (k>>3)&3, e = k&7
//   flat = tile*8192 + ki*512 + fq*128 + fm*8 + e
// => one MFMA fragment = 1KB contiguous; global_load_lds stages it with
//    per-lane global addr (base + lane*16B) and ds_read_b128 at lane*16B
//    is stride-1 (2 lanes/bank = conflict-free).

#define GLD_LDS(g, l) \
    __builtin_amdgcn_global_load_lds((__attribute__((address_space(1))) void*)(void*)(g), \
                                     (__attribute__((address_space(3))) void*)(l), 16, 0, 0)

// ---------------- shared LN row epilogue (wave holds one row of 512) -------
__device__ __forceinline__ void ln_row_write(float4 v0, float4 v1, int lane, size_t row,
                                             const float* __restrict__ gamma,
                                             const float* __restrict__ beta,
                                             float* HN, bf16* HNb) {
    float s = v0.x + v0.y + v0.z + v0.w + v1.x + v1.y + v1.z + v1.w;
    float q = v0.x * v0.x + v0.y * v0.y + v0.z * v0.z + v0.w * v0.w +
              v1.x * v1.x + v1.y * v1.y + v1.z * v1.z + v1.w * v1.w;
#pragma unroll
    for (int o = 1; o < 64; o <<= 1) {
        s += __shfl_xor(s, o);
        q += __shfl_xor(q, o);
    }
    float m = s * (1.0f / DD);
    float var = q * (1.0f / DD) - m * m;
    float rs = rsqrtf(var + EPSL);
    float4 g0 = *(const float4*)(gamma + lane * 4);
    float4 g1 = *(const float4*)(gamma + 256 + lane * 4);
    float4 b0 = *(const float4*)(beta + lane * 4);
    float4 b1 = *(const float4*)(beta + 256 + lane * 4);
    float4 o0, o1;
    o0.x = (v0.x - m) * rs * g0.x + b0.x;
    o0.y = (v0.y - m) * rs * g0.y + b0.y;
    o0.z = (v0.z - m) * rs * g0.z + b0.z;
    o0.w = (v0.w - m) * rs * g0.w + b0.w;
    o1.x = (v1.x - m) * rs * g1.x + b1.x;
    o1.y = (v1.y - m) * rs * g1.y + b1.y;
    o1.z = (v1.z - m) * rs * g1.z + b1.z;
    o1.w = (v1.w - m) * rs * g1.w + b1.w;
    float* hr = HN + row * DD;
    *(float4*)(hr + lane * 4) = o0;
    *(float4*)(hr + 256 + lane * 4) = o1;
    size_t pb = (size_t)(row >> 4) * 8192 + (size_t)(lane >> 3) * 512 +
                (size_t)((lane & 7) >> 1) * 128 + (row & 15) * 8 + (lane & 1) * 4;
    bf16x4 p0 = {(bf16)o0.x, (bf16)o0.y, (bf16)o0.z, (bf16)o0.w};
    bf16x4 p1 = {(bf16)o1.x, (bf16)o1.y, (bf16)o1.z, (bf16)o1.w};
    *(bf16x4*)(HNb + pb) = p0;
    *(bf16x4*)(HNb + pb + 8 * 512) = p1;
}

// ---------------- embed + layer-0 LN: X, HN, packed HNb in one pass --------
__global__ void embed_ln(const int* __restrict__ ids,
                         const float* __restrict__ eb,
                         const float* __restrict__ ep,
                         const float* __restrict__ gamma,
                         const float* __restrict__ beta,
                         float* __restrict__ X, float* HN, bf16* HNb) {
    int wave = threadIdx.x >> 6;
    int lane = threadIdx.x & 63;
    size_t row = blockIdx.x * 4 + wave;
    int s = (int)(row & (SS - 1));
    int id = ids[row];
    const float* ebr = eb + (size_t)id * DD;
    const float* epr = ep + (size_t)s * DD;
    float4 e0 = *(const float4*)(ebr + lane * 4);
    float4 e1 = *(const float4*)(ebr + 256 + lane * 4);
    float4 p0 = *(const float4*)(epr + lane * 4);
    float4 p1 = *(const float4*)(epr + 256 + lane * 4);
    float4 v0 = {e0.x + p0.x, e0.y + p0.y, e0.z + p0.z, e0.w + p0.w};
    float4 v1 = {e1.x + p1.x, e1.y + p1.y, e1.z + p1.z, e1.w + p1.w};
    *(float4*)(X + row * DD + lane * 4) = v0;
    *(float4*)(X + row * DD + 256 + lane * 4) = v1;
    ln_row_write(v0, v1, lane, row, gamma, beta, HN, HNb);
}

// ---------------- weight convert: coalesced LDS-slab transpose -> packed ---
// blk 0..255: layer n-tiles (l = blk>>6, tile = blk&63; tile<32 -> Wd, else WDp)
// blk 256..271: head n-tiles from Wh
__global__ __launch_bounds__(256) void convert_weights(const float* __restrict__ Wd,
                                                       const float* __restrict__ WDp,
                                                       const float* __restrict__ Wh,
                                                       bf16* __restrict__ WtP) {
    __shared__ float slab[512 * 17];
    int blk = blockIdx.x;
    const float* src;
    int nsrc, col0;
    bf16* dst;
    if (blk < 256) {
        int l = blk >> 6, tile = blk & 63;
        src = (tile < 32) ? (Wd + (size_t)l * DD * DD) : (WDp + (size_t)l * DD * DD);
        col0 = (tile & 31) * 16;
        nsrc = DD;
        dst = WtP + ((size_t)l * 64 + tile) * 8192;
    } else {
        int tile = blk - 256;
        src = Wh;
        col0 = tile * 16;
        nsrc = VV;
        dst = WtP + (size_t)(256 + tile) * 8192;
    }
    int tid = threadIdx.x;
    int kr = tid >> 2, cq = tid & 3;
#pragma unroll
    for (int i = 0; i < 8; i++) {
        int k = i * 64 + kr;
        float4 v = *(const float4*)(src + (size_t)k * nsrc + col0 + cq * 4);
        slab[k * 17 + cq * 4 + 0] = v.x;
        slab[k * 17 + cq * 4 + 1] = v.y;
        slab[k * 17 + cq * 4 + 2] = v.z;
        slab[k * 17 + cq * 4 + 3] = v.w;
    }
    __syncthreads();
#pragma unroll
    for (int it = 0; it < 4; it++) {
        int c = it * 256 + tid;
        int ki = c >> 6, fq = (c >> 4) & 3, fm = c & 15;
        int k0 = ki * 32 + fq * 8;
        bf16x8 v;
#pragma unroll
        for (int e = 0; e < 8; e++) v[e] = (bf16)slab[(k0 + e) * 17 + fm];
        *(bf16x8*)(dst + (size_t)c * 8) = v;
    }
}

// ---------------- MFMA GEMM: 64x64 tile, double-buffered staging -----------
// 2048-block grid (8 blocks/CU) for TLP; 2-phase dbuf hides the global->LDS
// latency under the current fragment's compute (stage issued BEFORE compute,
// vmcnt(0)-drain at the barrier covers loads issued one phase earlier).
// MODE 0 (head, NT=4): O1 = acc + bias
// MODE 1 (layer, NT=16): col<512 -> DEL=softplus; col>=512 -> D2=+bias2+Xres
template <int MODE, int NT>
__global__ __launch_bounds__(256, 8) void gemm_pack(const bf16* __restrict__ Ap,
                                                    const bf16* __restrict__ Bp,
                                                    const float* __restrict__ bias,
                                                    const float* __restrict__ bias2,
                                                    const float* __restrict__ Xres,
                                                    float* __restrict__ O1,
                                                    float* __restrict__ O2, int Nout) {
    __shared__ bf16 As[2][4 * 512];   // 2 x 4 KB
    __shared__ bf16 Bs[2][4 * 512];   // 2 x 4 KB
    const int tid = threadIdx.x, wave = tid >> 6, lane = tid & 63;
    const int lin = blockIdx.x;
    const int xcd = lin & 7, i4 = lin >> 3;
    const int ms = xcd * 16 + (i4 & 15);   // m-strip (64 rows), 128 total
    const int nb = i4 >> 4;                // n-tile (64 cols), NT total

    const bf16* gA = Ap + ((size_t)ms * 4 + wave) * 8192 + lane * 8;
    const bf16* gB = Bp + ((size_t)nb * 4 + wave) * 8192 + lane * 8;
    const int lo = wave * 512;

    const int fa0 = (wave >> 1) * 2, fb0 = (wave & 1) * 2;

    f32x4 acc[2][2];
#pragma unroll
    for (int i = 0; i < 2; i++)
#pragma unroll
        for (int j = 0; j < 2; j++) acc[i][j] = (f32x4){0.f, 0.f, 0.f, 0.f};

    // prologue: stage fragment 0 into buf 0
    GLD_LDS(gA, As[0] + lo);
    GLD_LDS(gB, Bs[0] + lo);
    __syncthreads();

#define COMPUTE(BUF)                                                                     \
    {                                                                                    \
        bf16x8 af[2], bfr[2];                                                            \
        _Pragma("unroll") for (int i = 0; i < 2; i++)                                    \
            af[i] = *(const bf16x8*)(As[BUF] + (fa0 + i) * 512 + lane * 8);              \
        _Pragma("unroll") for (int j = 0; j < 2; j++)                                    \
            bfr[j] = *(const bf16x8*)(Bs[BUF] + (fb0 + j) * 512 + lane * 8);             \
        _Pragma("unroll") for (int i = 0; i < 2; i++)                                    \
            _Pragma("unroll") for (int j = 0; j < 2; j++)                                \
                acc[i][j] = __builtin_amdgcn_mfma_f32_16x16x32_bf16(af[i], bfr[j],       \
                                                                   acc[i][j], 0, 0, 0); \
    }

#pragma unroll
    for (int ki = 0; ki < KI; ki += 2) {
        // phase A: prefetch ki+1 into buf1, compute ki from buf0
        if (ki + 1 < KI) {
            GLD_LDS(gA + (ki + 1) * 512, As[1] + lo);
            GLD_LDS(gB + (ki + 1) * 512, Bs[1] + lo);
        }
        COMPUTE(0);
        __syncthreads();   // drains vmcnt(0): buf1 ready; buf0 free to rewrite
        // phase B: prefetch ki+2 into buf0, compute ki+1 from buf1
        if (ki + 2 < KI) {
            GLD_LDS(gA + (ki + 2) * 512, As[0] + lo);
            GLD_LDS(gB + (ki + 2) * 512, Bs[0] + lo);
        }
        COMPUTE(1);
        __syncthreads();
    }
#undef COMPUTE

    const int fm = lane & 15, fq = lane >> 4;
#pragma unroll
    for (int i = 0; i < 2; i++) {
#pragma unroll
        for (int j = 0; j < 2; j++) {
            int col = (nb * 4 + fb0 + j) * 16 + fm;
#pragma unroll
            for (int r = 0; r < 4; r++) {
                int row = (ms * 4 + fa0 + i) * 16 + fq * 4 + r;
                float v = acc[i][j][r];
                if (MODE == 0) {
                    O1[(size_t)row * Nout + col] = v + bias[col];
                } else {
                    if (col < DD) {
                        v += bias[col];
                        v = fmaxf(v, 0.0f) + __logf(1.0f + __expf(-fabsf(v)));
                        O1[(size_t)row * DD + col] = v;
                    } else {
                        int c = col - DD;
                        O2[(size_t)row * DD + c] = v + bias2[c] + Xres[(size_t)row * DD + c];
                    }
                }
            }
        }
    }
}

// ---------------- fp32 B/C projection: [8192x512] x [512x32] ---------------
// Block: 32 rows x 32 cols, 256 threads, 4 rows/thread -> each W LDS read
// feeds 4 FMAs. Grid 256. W staged [k][32] (broadcast, conflict-free).
__global__ __launch_bounds__(256) void bcproj(const float* __restrict__ HN,
                                              const float* __restrict__ WB,
                                              const float* __restrict__ bB,
                                              const float* __restrict__ WC,
                                              const float* __restrict__ bC,
                                              float* __restrict__ BIo,
                                              float* __restrict__ CIo) {
    __shared__ float W[512 * 32];   // 64 KB
    int tid = threadIdx.x;
#pragma unroll
    for (int i = 0; i < 8; i++) {
        int f = i * 256 + tid;          // float4 index into WB/WC (2048 each)
        int k = f >> 2, c4 = (f & 3) * 4;
        float4 v = *(const float4*)(WB + (size_t)f * 4);
        W[k * 32 + c4 + 0] = v.x;
        W[k * 32 + c4 + 1] = v.y;
        W[k * 32 + c4 + 2] = v.z;
        W[k * 32 + c4 + 3] = v.w;
        float4 u = *(const float4*)(WC + (size_t)f * 4);
        W[k * 32 + 16 + c4 + 0] = u.x;
        W[k * 32 + 16 + c4 + 1] = u.y;
        W[k * 32 + 16 + c4 + 2] = u.z;
        W[k * 32 + 16 + c4 + 3] = u.w;
    }
    __syncthreads();
    int rg = tid >> 5, c = tid & 31;
    size_t row0 = (size_t)blockIdx.x * 32 + rg * 4;
    const float* h0 = HN + row0 * DD;
    const float* h1 = h0 + DD;
    const float* h2 = h1 + DD;
    const float* h3 = h2 + DD;
    float a0 = 0.f, a1 = 0.f, a2 = 0.f, a3 = 0.f;
#pragma unroll 4
    for (int k = 0; k < DD; k += 4) {
        float4 v0 = *(const float4*)(h0 + k);
        float4 v1 = *(const float4*)(h1 + k);
        float4 v2 = *(const float4*)(h2 + k);
        float4 v3 = *(const float4*)(h3 + k);
        float w0 = W[(k + 0) * 32 + c];
        float w1 = W[(k + 1) * 32 + c];
        float w2 = W[(k + 2) * 32 + c];
        float w3 = W[(k + 3) * 32 + c];
        a0 = fmaf(v0.x, w0, a0); a0 = fmaf(v0.y, w1, a0);
        a0 = fmaf(v0.z, w2, a0); a0 = fmaf(v0.w, w3, a0);
        a1 = fmaf(v1.x, w0, a1); a1 = fmaf(v1.y, w1, a1);
        a1 = fmaf(v1.z, w2, a1); a1 = fmaf(v1.w, w3, a1);
        a2 = fmaf(v2.x, w0, a2); a2 = fmaf(v2.y, w1, a2);
        a2 = fmaf(v2.z, w2, a2); a2 = fmaf(v2.w, w3, a2);
        a3 = fmaf(v3.x, w0, a3); a3 = fmaf(v3.y, w1, a3);
        a3 = fmaf(v3.z, w2, a3); a3 = fmaf(v3.w, w3, a3);
    }
    if (c < NN) {
        float bb = bB[c];
        BIo[(row0 + 0) * NN + c] = a0 + bb;
        BIo[(row0 + 1) * NN + c] = a1 + bb;
        BIo[(row0 + 2) * NN + c] = a2 + bb;
        BIo[(row0 + 3) * NN + c] = a3 + bb;
    } else {
        int cc = c - NN;
        float bb = bC[cc];
        CIo[(row0 + 0) * NN + cc] = a0 + bb;
        CIo[(row0 + 1) * NN + cc] = a1 + bb;
        CIo[(row0 + 2) * NN + cc] = a2 + bb;
        CIo[(row0 + 3) * NN + cc] = a3 + bb;
    }
}

// ---------------- scan phase 1: pure register chunk scan --------------------
// Block (b,c): 512 threads (one per d). Chunk decay prod is exp(Ar*sum(dl)):
// store ONLY sdl (1 float per (b,c,d)) -- scan2 recomputes p identically.
__global__ __launch_bounds__(512) void scan1(const float* __restrict__ DEL,
                                             const float* __restrict__ HN,
                                             const float* __restrict__ BIc,
                                             const float* __restrict__ logA,
                                             float* __restrict__ SDL,
                                             float* __restrict__ LSt) {
    __shared__ float bis[TT * NN];   // 1 KB
    int b = blockIdx.x >> 7, c = blockIdx.x & (CC - 1);
    int d = threadIdx.x;
    size_t row0 = (size_t)b * SS + (size_t)c * TT;
    if (d < TT * NN) bis[d] = BIc[row0 * NN + d];
    float Ar[NN], st[NN];
    const float* la = logA + d * NN;
#pragma unroll
    for (int n = 0; n < NN; n += 4) {
        float4 a4 = *(const float4*)(la + n);
        Ar[n + 0] = -__expf(a4.x);
        Ar[n + 1] = -__expf(a4.y);
        Ar[n + 2] = -__expf(a4.z);
        Ar[n + 3] = -__expf(a4.w);
    }
#pragma unroll
    for (int n = 0; n < NN; n++) st[n] = 0.0f;
    float sdl = 0.0f;
    __syncthreads();
    const float* dp = DEL + row0 * DD + d;
    const float* hp = HN + row0 * DD + d;
#pragma unroll 4
    for (int tt = 0; tt < TT; tt++) {
        float dl = dp[(size_t)tt * DD];
        float du = dl * hp[(size_t)tt * DD];
        sdl += dl;
#pragma unroll
        for (int n = 0; n < NN; n++) {
            float a = __expf(dl * Ar[n]);
            st[n] = fmaf(a, st[n], du * bis[tt * NN + n]);
        }
    }
    SDL[((size_t)b * CC + c) * DD + d] = sdl;
    size_t o = (((size_t)b * CC + c) * DD + d) * NN;
#pragma unroll
    for (int n = 0; n < NN; n += 4)
        *(f32x4*)(LSt + o + n) = (f32x4){st[n], st[n + 1], st[n + 2], st[n + 3]};
}

// ---------------- scan phase 2: parallel affine-compose combine ------------
// Block per (b,d): 256 threads = 16 n x 16 groups of 8 chunks. p recomputed
// from SDL (bitwise-identical to scan1's formula). Re-walk writes exclusive
// chunk-initial states into LS in place.
__global__ __launch_bounds__(256) void scan2(const float* __restrict__ SDL,
                                             const float* __restrict__ logA,
                                             float* __restrict__ LS) {
    __shared__ float sP[256], sL[256];
    int bd = blockIdx.x;                       // b*DD + d
    int b = bd >> 9, d = bd & (DD - 1);
    int n = threadIdx.x & (NN - 1), g = threadIdx.x >> 4;
    float Ar = -__expf(logA[d * NN + n]);
    size_t base = ((size_t)b * CC * DD + d) * NN + n;
    size_t sbase = (size_t)b * CC * DD + d;
    const size_t cs = (size_t)DD * NN;         // LS stride between chunks
    float p[8], l[8];
#pragma unroll
    for (int i = 0; i < 8; i++) {
        int c = g * 8 + i;
        p[i] = __expf(Ar * SDL[sbase + (size_t)c * DD]);
        l[i] = LS[base + (size_t)c * cs];
    }
    float FP = 1.0f, FL = 0.0f;
#pragma unroll
    for (int i = 0; i < 8; i++) {
        FL = fmaf(p[i], FL, l[i]);
        FP *= p[i];
    }
    sP[threadIdx.x] = FP;
    sL[threadIdx.x] = FL;
    __syncthreads();
    if (threadIdx.x < NN) {
        int nn = threadIdx.x;
        float s = 0.0f;
#pragma unroll
        for (int gg = 0; gg < 16; gg++) {
            float fp = sP[gg * 16 + nn];
            float fl = sL[gg * 16 + nn];
            sL[gg * 16 + nn] = s;              // exclusive group-initial state
            s = fmaf(fp, s, fl);
        }
    }
    __syncthreads();
    float s = sL[g * 16 + n];
#pragma unroll
    for (int i = 0; i < 8; i++) {
        size_t o = base + (size_t)(g * 8 + i) * cs;
        LS[o] = s;                             // chunk-initial state
        s = fmaf(p[i], s, l[i]);
    }
}

// ---------------- scan3 + fused next-layer LN -------------------------------
template <int LAST>
__global__ __launch_bounds__(512) void scan3ln(const float* __restrict__ DEL,
                                               float* HN,
                                               const float* __restrict__ BI,
                                               const float* __restrict__ CI,
                                               const float* __restrict__ logA,
                                               const float* __restrict__ SIN,
                                               const float* __restrict__ D2,
                                               const float* __restrict__ gamma,
                                               const float* __restrict__ beta,
                                               float* __restrict__ X,
                                               bf16* HNb) {
    __shared__ float xvs[TT * LPAD];    // 33.8 KB
    __shared__ float bis[TT * NN], cis[TT * NN];
    int b = blockIdx.x >> 7, c = blockIdx.x & (CC - 1);
    int d = threadIdx.x;
    size_t row0 = (size_t)b * SS + (size_t)c * TT;
    if (d < TT * NN) {
        bis[d] = BI[row0 * NN + d];
        cis[d] = CI[row0 * NN + d];
    }
    float Ar[NN], st[NN];
    size_t o = (((size_t)b * CC + c) * DD + d) * NN;
    const float* la = logA + d * NN;
#pragma unroll
    for (int n = 0; n < NN; n += 4) {
        float4 a4 = *(const float4*)(la + n);
        Ar[n + 0] = -__expf(a4.x);
        Ar[n + 1] = -__expf(a4.y);
        Ar[n + 2] = -__expf(a4.z);
        Ar[n + 3] = -__expf(a4.w);
        float4 s4 = *(const float4*)(SIN + o + n);
        st[n + 0] = s4.x;
        st[n + 1] = s4.y;
        st[n + 2] = s4.z;
        st[n + 3] = s4.w;
    }
    __syncthreads();
    const float* dp = DEL + row0 * DD + d;
    const float* hp = HN + row0 * DD + d;
    const float* d2p = D2 + row0 * DD + d;
    float* xp = X + row0 * DD + d;
#pragma unroll 4
    for (int tt = 0; tt < TT; tt++) {
        float dl = dp[(size_t)tt * DD];
        float du = dl * hp[(size_t)tt * DD];
        float y = 0.0f;
#pragma unroll
        for (int n = 0; n < NN; n++) {
            float a = __expf(dl * Ar[n]);
            st[n] = fmaf(a, st[n], du * bis[tt * NN + n]);
            y = fmaf(st[n], cis[tt * NN + n], y);
        }
        float xv = d2p[(size_t)tt * DD] + y;
        xvs[tt * LPAD + d] = xv;
        if (!LAST) xp[(size_t)tt * DD] = xv;
    }
    __syncthreads();
    int wv = d >> 6, lane = d & 63;
#pragma unroll
    for (int r = 0; r < 2; r++) {
        int tt = wv * 2 + r;
        size_t row = row0 + tt;
        const float* xr = xvs + tt * LPAD;
        float4 v0 = *(const float4*)(xr + lane * 4);
        float4 v1 = *(const float4*)(xr + 256 + lane * 4);
        if (LAST) {
            size_t pb = (size_t)(row >> 4) * 8192 + (size_t)(lane >> 3) * 512 +
                        (size_t)((lane & 7) >> 1) * 128 + (row & 15) * 8 + (lane & 1) * 4;
            bf16x4 p0 = {(bf16)v0.x, (bf16)v0.y, (bf16)v0.z, (bf16)v0.w};
            bf16x4 p1 = {(bf16)v1.x, (bf16)v1.y, (bf16)v1.z, (bf16)v1.w};
            *(bf16x4*)(HNb + pb) = p0;
            *(bf16x4*)(HNb + pb + 8 * 512) = p1;
        } else {
            ln_row_write(v0, v1, lane, row, gamma, beta, HN, HNb);
        }
    }
}

extern "C" void kernel_launch(void* const* d_in, const int* in_sizes, int n_in,
                              void* d_out, int out_size, void* d_ws, size_t ws_size,
                              hipStream_t stream) {
    const int* ids = (const int*)d_in[0];
    const float* eb = (const float*)d_in[1];
    const float* ep = (const float*)d_in[2];
    const float* logA = (const float*)d_in[3];
    const float* Wd = (const float*)d_in[4];
    const float* bd = (const float*)d_in[5];
    const float* WB = (const float*)d_in[6];
    const float* bB = (const float*)d_in[7];
    const float* WC = (const float*)d_in[8];
    const float* bC = (const float*)d_in[9];
    const float* WDp = (const float*)d_in[10];
    const float* bDp = (const float*)d_in[11];
    const float* gamma = (const float*)d_in[12];
    const float* beta = (const float*)d_in[13];
    const float* Wh = (const float*)d_in[14];
    const float* bh = (const float*)d_in[15];
    float* out = (float*)d_out;

    size_t E = (size_t)MM * DD;                // 4,194,304 floats
    size_t EN = (size_t)MM * NN;               // 131,072
    // Aliasing: SDL = X (X dead between gemm_pack (reads Xres) and scan3ln
    // (rewrites all of X); SDL consumed by scan2 before scan3 runs).
    // BIc/CIc live in d_out (dead until head writes).
    float* X = (float*)d_ws;
    float* HN = X + E;
    float* DEL = HN + E;
    float* D2 = DEL + E;
    float* LS = D2 + E;
    bf16* HNb = (bf16*)(LS + E);               // packed activations, 8 MB
    bf16* WtP = HNb + E;                       // packed weights: 272 tiles
    float* SDL = X;
    float* BIc = out;
    float* CIc = out + EN;

    embed_ln<<<MM / 4, 256, 0, stream>>>(ids, eb, ep, gamma, beta, X, HN, HNb);
    convert_weights<<<272, 256, 0, stream>>>(Wd, WDp, Wh, WtP);
    for (int l = 0; l < LL; l++) {
        const float* lA = logA + (size_t)l * DD * NN;
        bcproj<<<MM / 32, 256, 0, stream>>>(HN, WB + (size_t)l * DD * NN, bB + l * NN,
                                            WC + (size_t)l * DD * NN, bC + l * NN,
                                            BIc, CIc);
        gemm_pack<1, 16><<<2048, 256, 0, stream>>>(
            HNb, WtP + (size_t)l * 524288, bd + l * DD, bDp + l * DD, X, DEL, D2, 1024);
        scan1<<<BB * CC, 512, 0, stream>>>(DEL, HN, BIc, lA, SDL, LS);
        scan2<<<BB * DD, 256, 0, stream>>>(SDL, lA, LS);
        if (l < LL - 1) {
            scan3ln<0><<<BB * CC, 512, 0, stream>>>(DEL, HN, BIc, CIc, lA, LS, D2,
                                                    gamma + (l + 1) * DD, beta + (l + 1) * DD,
                                                    X, HNb);
        } else {
            scan3ln<1><<<BB * CC, 512, 0, stream>>>(DEL, HN, BIc, CIc, lA, LS, D2,
                                                    nullptr, nullptr, X, HNb);
        }
    }
    // head: reads packed bf16(X_final) written by last scan3ln
    gemm_pack<0, 4><<<512, 256, 0, stream>>>(
        HNb, WtP + (size_t)2097152, bh, nullptr, nullptr, out, nullptr, VV);
}